// Round 8
// baseline (28.350 us; speedup 1.0000x reference)
//
#include <hip/hip_runtime.h>

// Problem shape (fixed by reference setup_inputs)
#define BB 8
#define SS 8192
#define CC 256

#define NBLK 256                 // 8 b x 16 col-slices x 2 s-halves, 1 block/CU
#define HALF (SS / 2)            // 4096 rows per s-half
#define NW 16                    // waves per block (1024 threads)
#define PASSES (HALF / 256)      // 16 float4 loads per thread

// ws layout (overwritten every call -> no init, no atomics, deterministic):
//   ws1[2][2048]  complete per-(s-half) column sums, float4-friendly (16 KB)
//   ws2[NBLK]     per-block sum-of-squares partials (1 KB)

__global__ __launch_bounds__(1024) void pcl_partial(const float* __restrict__ x,
                                                    float* __restrict__ ws1,
                                                    float* __restrict__ ws2) {
    const int blk = blockIdx.x;
    const int b   = blk >> 5;           // batch
    const int r   = blk & 31;
    const int cs  = r >> 1;             // col-slice 0..15 (16 cols = 64 B)
    const int sh  = r & 1;              // s-half
    const int t = threadIdx.x;
    const int w = t >> 6;               // wave 0..15
    const int l = t & 63;               // lane
    const int rq = t >> 2;              // row-within-pass 0..255
    const int cq = t & 3;               // float4 within the 16-col slice

    // Each pass: 256 consecutive rows, this block's 64-B slice of each row.
    // Wave-instr = 16 rows x 64 B (full cache lines).
    const float4* p = reinterpret_cast<const float4*>(x)
        + ((size_t)b * SS + (size_t)sh * HALF + rq) * (CC / 4) + cs * 4 + cq;

    float4 s4 = make_float4(0.f, 0.f, 0.f, 0.f);
    float sqa = 0.f, sqb = 0.f;
    #pragma unroll                       // 16 independent loads in flight
    for (int k = 0; k < PASSES; ++k) {
        float4 v = p[(size_t)k * 256 * (CC / 4)];
        s4.x += v.x; s4.y += v.y; s4.z += v.z; s4.w += v.w;
        sqa += v.x * v.x + v.y * v.y;
        sqb += v.z * v.z + v.w * v.w;
    }

    // Wave-reduce col partials over the 16 row-slots (stride-4 butterfly);
    // lanes 0..3 end with the wave's sums for cq=0..3.
    for (int off = 32; off >= 4; off >>= 1) {
        s4.x += __shfl_down(s4.x, off, 64);
        s4.y += __shfl_down(s4.y, off, 64);
        s4.z += __shfl_down(s4.z, off, 64);
        s4.w += __shfl_down(s4.w, off, 64);
    }
    __shared__ float4 wsum[NW][4];       // 1 KB
    if (l < 4) wsum[w][l] = s4;

    // Wave-reduce sum of squares (full 64-lane)
    float sq = sqa + sqb;
    for (int off = 32; off > 0; off >>= 1) sq += __shfl_down(sq, off, 64);
    __shared__ float x2buf[NW];
    if (l == 0) x2buf[w] = sq;
    __syncthreads();

    // One wave folds the 16 waves' partials (stride-4 again); lanes 0..3 store.
    if (t < 64) {
        const int wv = t >> 2, c = t & 3;
        float4 v = wsum[wv][c];
        for (int off = 32; off >= 4; off >>= 1) {
            v.x += __shfl_down(v.x, off, 64);
            v.y += __shfl_down(v.y, off, 64);
            v.z += __shfl_down(v.z, off, 64);
            v.w += __shfl_down(v.w, off, 64);
        }
        if (t < 4)   // t == c here
            reinterpret_cast<float4*>(ws1)[sh * 512 + b * 64 + cs * 4 + t] = v;
    }
    if (t == 0) {
        float s2 = 0.f;
        #pragma unroll
        for (int g = 0; g < NW; ++g) s2 += x2buf[g];
        ws2[blk] = s2;
    }
}

__global__ __launch_bounds__(512) void pcl_final(const float* __restrict__ ws1,
                                                 const float* __restrict__ ws2,
                                                 float* __restrict__ out) {
    const int t = threadIdx.x;           // 0..511, one float4 of columns each
    const float4* w4 = reinterpret_cast<const float4*>(ws1);
    const float4 a = w4[t];              // s-half 0
    const float4 c = w4[512 + t];        // s-half 1
    const float inv_s = 1.0f / SS;
    const float m0 = (a.x + c.x) * inv_s, m1 = (a.y + c.y) * inv_s,
                m2 = (a.z + c.z) * inv_s, m3 = (a.w + c.w) * inv_s;
    float P = -(m0 * m0 + m1 * m1 + m2 * m2 + m3 * m3) * (1.0f / (BB * CC));
    if (t < NBLK) P += ws2[t] * (1.0f / ((float)BB * SS * CC));

    for (int off = 32; off > 0; off >>= 1) P += __shfl_down(P, off, 64);
    __shared__ float buf[8];
    if ((t & 63) == 0) buf[t >> 6] = P;
    __syncthreads();
    if (t == 0) {
        float tot = 0.f;
        #pragma unroll
        for (int i = 0; i < 8; ++i) tot += buf[i];
        out[0] = 0.2f * tot;    // 0.1 (weight) * 2 (pairwise->variance identity)
    }
}

extern "C" void kernel_launch(void* const* d_in, const int* in_sizes, int n_in,
                              void* d_out, int out_size, void* d_ws, size_t ws_size,
                              hipStream_t stream) {
    const float* x = (const float*)d_in[0];
    float* ws1 = (float*)d_ws;              // 2*2048 floats (complete col sums)
    float* ws2 = ws1 + 2 * 2048;            // NBLK floats (sq partials)
    float* out = (float*)d_out;

    pcl_partial<<<NBLK, 1024, 0, stream>>>(x, ws1, ws2);
    pcl_final<<<1, 512, 0, stream>>>(ws1, ws2, out);
}

// Round 9
// 22.082 us; speedup vs baseline: 1.2839x; 1.2839x over previous
//
#include <hip/hip_runtime.h>

// Problem shape (fixed by reference setup_inputs)
#define BB 8
#define SS 8192
#define CC 256

#define NBLK 256                        // 1 block per CU
#define CPB (NBLK / BB)                 // 32 s-chunks per batch
#define SCHUNK (SS / CPB)               // 256 rows per block
#define NW 16                           // waves per block (1024 threads)
#define ITERS (SCHUNK / NW)             // 16 float4 row-loads per thread

// ws layout (all overwritten every call -> no init needed, deterministic):
//   ws1[NBLK][CC]  per-block column partial sums    (256 KB)
//   ws2[NBLK]      per-block sum-of-squares partials  (1 KB)
//   ws3[32]        per-mid-block folded scalars       (128 B)
//   counter        last-done atomic counter (zeroed by phase 1 each call)

__global__ __launch_bounds__(1024) void pcl_partial(const float* __restrict__ x,
                                                    float* __restrict__ ws1,
                                                    float* __restrict__ ws2,
                                                    unsigned int* __restrict__ counter) {
    const int blk   = blockIdx.x;
    const int b     = blk >> 5;         // blk / CPB
    const int chunk = blk & 31;
    const int s0    = chunk * SCHUNK;
    const int t = threadIdx.x;
    const int w = t >> 6;               // wave 0..15
    const int l = t & 63;               // lane

    if (blk == 0 && t == 0) *counter = 0u;   // stream-ordered before dispatch 2

    // Wave w reads full contiguous 1 KB rows s0+w, s0+w+16, ... (16 rows).
    const float4* p = reinterpret_cast<const float4*>(
        x + ((size_t)b * SS + (size_t)(s0 + w)) * CC) + l;

    float sx0 = 0.f, sx1 = 0.f, sx2 = 0.f, sx3 = 0.f;
    float sqa = 0.f, sqb = 0.f;         // two chains: shorter dependency
    #pragma unroll                      // full: 16 independent loads in flight
    for (int k = 0; k < ITERS; ++k) {
        float4 v = p[(size_t)k * (NW * CC / 4)];   // advance 16 rows
        sx0 += v.x; sx1 += v.y; sx2 += v.z; sx3 += v.w;
        sqa += v.x * v.x + v.y * v.y;
        sqb += v.z * v.z + v.w * v.w;
    }
    float sq = sqa + sqb;

    // Combine the 16 waves' column partials through LDS (16 KB).
    __shared__ float lsum[NW][CC];
    *reinterpret_cast<float4*>(&lsum[w][l * 4]) = make_float4(sx0, sx1, sx2, sx3);

    // Wave-reduce sum of squares
    for (int off = 32; off > 0; off >>= 1) sq += __shfl_down(sq, off, 64);
    __shared__ float x2buf[NW];
    if (l == 0) x2buf[w] = sq;
    __syncthreads();

    if (t < CC) {
        float col = 0.f;
        #pragma unroll
        for (int g = 0; g < NW; ++g) col += lsum[g][t];
        ws1[blk * CC + t] = col;
    }
    if (t == 0) {
        float s2 = 0.f;
        #pragma unroll
        for (int g = 0; g < NW; ++g) s2 += x2buf[g];
        ws2[blk] = s2;
    }
}

// 32 blocks: block k = (batch b = k>>2, 64 columns starting at (k&3)*64).
// Completes its column sums, applies mean^2, folds 8 ws2 partials, then the
// LAST block to finish (device-scope counter) folds the 32 scalars -> out.
__global__ __launch_bounds__(256) void pcl_mid(const float* __restrict__ ws1,
                                               const float* __restrict__ ws2,
                                               float* __restrict__ ws3,
                                               unsigned int* __restrict__ counter,
                                               float* __restrict__ out) {
    const int k  = blockIdx.x;          // 0..31
    const int b  = k >> 2;
    const int c0 = (k & 3) * 64;
    const int t  = threadIdx.x;
    const int w  = t >> 6;              // 0..3 -> chunk groups of 8
    const int l  = t & 63;              // column within group

    // 8 coalesced 256 B reads per wave, stride 1 KB (L2/L3-hot).
    const float* base = ws1 + (size_t)(b * CPB + w * 8) * CC + c0 + l;
    float s = 0.f;
    #pragma unroll
    for (int j = 0; j < 8; ++j) s += base[(size_t)j * CC];

    __shared__ float sL[4][64];
    sL[w][l] = s;
    __shared__ bool isLast;
    __syncthreads();

    if (t < 64) {
        const float col = sL[0][t] + sL[1][t] + sL[2][t] + sL[3][t];
        const float m   = col * (1.0f / SS);
        float P = -m * m * (1.0f / (BB * CC));
        if (t < 8) P += ws2[k * 8 + t] * (1.0f / ((float)BB * SS * CC));
        for (int off = 32; off > 0; off >>= 1) P += __shfl_down(P, off, 64);
        if (t == 0) {
            ws3[k] = P;
            __threadfence();            // publish ws3[k] device-wide
            unsigned int old = atomicAdd(counter, 1u);   // device scope
            isLast = (old == 31u);
        }
    }
    __syncthreads();
    if (!isLast) return;

    // Last block folds the 32 per-block scalars.
    __threadfence();                    // acquire side
    if (t < 64) {
        float P = 0.f;
        if (t < 32)
            P = __hip_atomic_load(&ws3[t], __ATOMIC_RELAXED,
                                  __HIP_MEMORY_SCOPE_AGENT);
        for (int off = 32; off > 0; off >>= 1) P += __shfl_down(P, off, 64);
        if (t == 0) out[0] = 0.2f * P;  // 0.1 (weight) * 2 (pairwise->variance)
    }
}

extern "C" void kernel_launch(void* const* d_in, const int* in_sizes, int n_in,
                              void* d_out, int out_size, void* d_ws, size_t ws_size,
                              hipStream_t stream) {
    const float* x = (const float*)d_in[0];
    float* ws1 = (float*)d_ws;                      // NBLK*CC floats
    float* ws2 = ws1 + NBLK * CC;                   // NBLK floats
    float* ws3 = ws2 + NBLK;                        // 32 floats
    unsigned int* counter = (unsigned int*)(ws3 + 32);
    float* out = (float*)d_out;

    pcl_partial<<<NBLK, 1024, 0, stream>>>(x, ws1, ws2, counter);
    pcl_mid<<<32, 256, 0, stream>>>(ws1, ws2, ws3, counter, out);
}

// Round 10
// 21.150 us; speedup vs baseline: 1.3404x; 1.0440x over previous
//
#include <hip/hip_runtime.h>

// Problem shape (fixed by reference setup_inputs)
#define BB 8
#define SS 8192
#define CC 256

#define NBLK 256                        // 1 block per CU
#define CPB (NBLK / BB)                 // 32 s-chunks per batch
#define SCHUNK (SS / CPB)               // 256 rows per block
#define NW 16                           // waves per block (1024 threads)
#define ITERS (SCHUNK / NW)             // 16 float4 row-loads per thread

// ws layout: ws1[NBLK][CC] per-block column partial sums (256 KB),
//            ws2[NBLK]      per-block sum-of-squares partials (1 KB).
// Plain overwriting stores every call -> no init, no atomics, deterministic.
//
// Session accounting (R0-R9): fixed graph-replay overhead ~14 us; phase 1
// ~4.5-5 us (L2/L3-resident input, near cache-BW bound); gap ~1.5 us;
// finale ~1-2 us. Coop grid.sync costs +40 us (R6); flag-barrier fusion
// +6 us (R7); column-slice partitioning +7 us (R8); tail parallelization
// neutral (R5/R9). This 2-dispatch contiguous-stream structure is the best
// measured configuration (21.0 us, R4).

__global__ __launch_bounds__(1024) void pcl_partial(const float* __restrict__ x,
                                                    float* __restrict__ ws1,
                                                    float* __restrict__ ws2) {
    const int blk   = blockIdx.x;
    const int b     = blk >> 5;         // blk / CPB
    const int chunk = blk & 31;
    const int s0    = chunk * SCHUNK;
    const int t = threadIdx.x;
    const int w = t >> 6;               // wave 0..15
    const int l = t & 63;               // lane

    // Wave w reads full contiguous 1 KB rows s0+w, s0+w+16, ... (16 rows).
    // Block region = 256 contiguous rows = 256 KB sequential stream.
    const float4* p = reinterpret_cast<const float4*>(
        x + ((size_t)b * SS + (size_t)(s0 + w)) * CC) + l;

    float sx0 = 0.f, sx1 = 0.f, sx2 = 0.f, sx3 = 0.f;
    float sqa = 0.f, sqb = 0.f;         // two chains: shorter dependency
    #pragma unroll                      // full: 16 independent loads in flight
    for (int k = 0; k < ITERS; ++k) {
        float4 v = p[(size_t)k * (NW * CC / 4)];   // advance 16 rows
        sx0 += v.x; sx1 += v.y; sx2 += v.z; sx3 += v.w;
        sqa += v.x * v.x + v.y * v.y;
        sqb += v.z * v.z + v.w * v.w;
    }
    float sq = sqa + sqb;

    // Combine the 16 waves' column partials through LDS (16 KB).
    __shared__ float lsum[NW][CC];
    *reinterpret_cast<float4*>(&lsum[w][l * 4]) = make_float4(sx0, sx1, sx2, sx3);

    // Wave-reduce sum of squares
    for (int off = 32; off > 0; off >>= 1) sq += __shfl_down(sq, off, 64);
    __shared__ float x2buf[NW];
    if (l == 0) x2buf[w] = sq;
    __syncthreads();

    if (t < CC) {
        float col = 0.f;
        #pragma unroll
        for (int g = 0; g < NW; ++g) col += lsum[g][t];   // contiguous -> no conflict
        ws1[blk * CC + t] = col;
    }
    if (t == 0) {
        float s2 = 0.f;
        #pragma unroll
        for (int g = 0; g < NW; ++g) s2 += x2buf[g];
        ws2[blk] = s2;
    }
}

__global__ __launch_bounds__(1024) void pcl_final(const float* __restrict__ ws1,
                                                  const float* __restrict__ ws2,
                                                  float* __restrict__ out) {
    const int t = threadIdx.x;          // 0..1023
    float P = 0.f;

    if (t < 512) {
        const int b  = t >> 6;          // 0..7
        const int cq = t & 63;          // float4 column group
        // colsum[b][4cq..4cq+3] = sum over 32 chunk-partials (L2/L3-hot).
        const float4* p4 = reinterpret_cast<const float4*>(ws1)
                           + (size_t)(b * CPB) * (CC / 4) + cq;
        float4 s = make_float4(0.f, 0.f, 0.f, 0.f);
        #pragma unroll 8
        for (int ch = 0; ch < CPB; ++ch) {
            float4 v = p4[(size_t)ch * (CC / 4)];
            s.x += v.x; s.y += v.y; s.z += v.z; s.w += v.w;
        }
        const float inv_s = 1.0f / SS;
        const float m0 = s.x * inv_s, m1 = s.y * inv_s,
                    m2 = s.z * inv_s, m3 = s.w * inv_s;
        P = -(m0 * m0 + m1 * m1 + m2 * m2 + m3 * m3) * (1.0f / (BB * CC));
    } else if (t < 512 + NBLK) {
        P = ws2[t - 512] * (1.0f / ((float)BB * SS * CC));
    }

    for (int off = 32; off > 0; off >>= 1) P += __shfl_down(P, off, 64);
    __shared__ float buf[16];
    if ((t & 63) == 0) buf[t >> 6] = P;
    __syncthreads();
    if (t == 0) {
        float tot = 0.f;
        #pragma unroll
        for (int i = 0; i < 16; ++i) tot += buf[i];
        out[0] = 0.2f * tot;    // 0.1 (weight) * 2 (pairwise->variance identity)
    }
}

extern "C" void kernel_launch(void* const* d_in, const int* in_sizes, int n_in,
                              void* d_out, int out_size, void* d_ws, size_t ws_size,
                              hipStream_t stream) {
    const float* x = (const float*)d_in[0];
    float* ws1 = (float*)d_ws;              // NBLK*CC floats
    float* ws2 = ws1 + NBLK * CC;           // NBLK floats
    float* out = (float*)d_out;

    pcl_partial<<<NBLK, 1024, 0, stream>>>(x, ws1, ws2);
    pcl_final<<<1, 1024, 0, stream>>>(ws1, ws2, out);
}